// Round 1
// baseline (705.891 us; speedup 1.0000x reference)
//
#include <hip/hip_runtime.h>
#include <hip/hip_bf16.h>

#define BB 4
#define SS 2048
#define DD 2048
#define HH 16
#define HDD 128

typedef __bf16 bf16x8_t __attribute__((ext_vector_type(8)));
typedef float f32x4 __attribute__((ext_vector_type(4)));

static __device__ __forceinline__ unsigned short f2bf(float f) {
    union { float f; unsigned u; } v; v.f = f;
    unsigned r = v.u + 0x7fffu + ((v.u >> 16) & 1u);
    return (unsigned short)(r >> 16);
}

static __device__ __forceinline__ void gload_lds16(const void* g, void* lds) {
    __builtin_amdgcn_global_load_lds(
        (const __attribute__((address_space(1))) void*)g,
        (__attribute__((address_space(3))) void*)lds, 16, 0, 0);
}

// ---------------- convert x fp32 -> bf16 ----------------
__global__ void convert_x(const float* __restrict__ x, unsigned short* __restrict__ xb, int n) {
    int i = (blockIdx.x * blockDim.x + threadIdx.x) * 4;
    int stride = gridDim.x * blockDim.x * 4;
    for (; i < n; i += stride) {
        float4 v = *(const float4*)(x + i);
        ushort4 o;
        o.x = f2bf(v.x); o.y = f2bf(v.y); o.z = f2bf(v.z); o.w = f2bf(v.w);
        *(ushort4*)(xb + i) = o;
    }
}

// ---------------- transpose + convert weights: T[n][k] = W[k][n] ----------------
__global__ void transpose_w(const float* __restrict__ Wq, const float* __restrict__ Wk,
                            const float* __restrict__ Wv, const float* __restrict__ Wo,
                            unsigned short* __restrict__ WqkvT, unsigned short* __restrict__ WoT) {
    __shared__ float t[32][33];
    const int z = blockIdx.z;
    const float* W = (z == 0) ? Wq : (z == 1) ? Wk : (z == 2) ? Wv : Wo;
    unsigned short* T = (z < 3) ? (WqkvT + (size_t)z * DD * DD) : WoT;
    const int k0 = blockIdx.x * 32, n0 = blockIdx.y * 32;
    const int tx = threadIdx.x, ty = threadIdx.y;
#pragma unroll
    for (int i = 0; i < 4; ++i) {
        int r = ty + i * 8;
        t[r][tx] = W[(size_t)(k0 + r) * DD + n0 + tx];
    }
    __syncthreads();
#pragma unroll
    for (int i = 0; i < 4; ++i) {
        int r = ty + i * 8;
        T[(size_t)(n0 + r) * DD + k0 + tx] = f2bf(t[tx][r]);
    }
}

// ---------------- transpose V [bh][s][hd] -> VT [bh][hd][s] ----------------
__global__ void transpose_v(const unsigned short* __restrict__ V, unsigned short* __restrict__ VT) {
    __shared__ unsigned short t[32][33];
    const int bh = blockIdx.z;
    const int s0 = blockIdx.x * 32, d0 = blockIdx.y * 32;
    const unsigned short* Vb = V + (size_t)bh * SS * HDD;
    unsigned short* Tb = VT + (size_t)bh * HDD * SS;
    const int tx = threadIdx.x, ty = threadIdx.y;
#pragma unroll
    for (int i = 0; i < 4; ++i) {
        int r = ty + i * 8;
        t[r][tx] = Vb[(size_t)(s0 + r) * HDD + d0 + tx];
    }
    __syncthreads();
#pragma unroll
    for (int i = 0; i < 4; ++i) {
        int r = ty + i * 8;
        Tb[(size_t)(d0 + r) * SS + s0 + tx] = t[tx][r];
    }
}

// ---------------- GEMM: C[M][N] = A[M][K] * BT[N][K]^T, bf16 in, MODE 0: QKV bf16 out; MODE 1: fp32 out + bias ----------------
template <int MODE>
__global__ __launch_bounds__(256, 2) void gemm_bt(
    const unsigned short* __restrict__ A, const unsigned short* __restrict__ BT,
    unsigned short* __restrict__ outQ, unsigned short* __restrict__ outK,
    unsigned short* __restrict__ outV, float* __restrict__ outF,
    const float* __restrict__ bias) {
    __shared__ __attribute__((aligned(16))) unsigned short As[2][128 * 32];
    __shared__ __attribute__((aligned(16))) unsigned short Bs[2][128 * 32];
    const int tid = threadIdx.x;
    const int w = tid >> 6, l = tid & 63;
    const int wr = w >> 1, wc = w & 1;
    const int m0 = blockIdx.y * 128;
    const int n0 = blockIdx.x * 128;

    f32x4 acc[4][4] = {};

    auto stage = [&](int buf, int kt) {
        const int k0 = kt * 32;
#pragma unroll
        for (int iss = 0; iss < 2; ++iss) {
            int row = w * 32 + iss * 16 + (l >> 2);
            int kb = (l & 3) * 16;
            const char* ga = (const char*)A + ((size_t)(m0 + row) * DD + k0) * 2 + kb;
            gload_lds16(ga, (char*)&As[buf][0] + (w * 32 + iss * 16) * 64);
            const char* gb = (const char*)BT + ((size_t)(n0 + row) * DD + k0) * 2 + kb;
            gload_lds16(gb, (char*)&Bs[buf][0] + (w * 32 + iss * 16) * 64);
        }
    };

    int cur = 0;
    stage(0, 0);
    __syncthreads();
    const int lrow = l & 15, lko = (l >> 4) * 16;
    for (int t = 0; t < 64; ++t) {
        if (t + 1 < 64) stage(cur ^ 1, t + 1);
        const char* Ab = (const char*)&As[cur][0];
        const char* Bb = (const char*)&Bs[cur][0];
        bf16x8_t af[4], bfg[4];
#pragma unroll
        for (int i = 0; i < 4; ++i)
            af[i] = *(const bf16x8_t*)(Ab + (wr * 64 + i * 16 + lrow) * 64 + lko);
#pragma unroll
        for (int j = 0; j < 4; ++j)
            bfg[j] = *(const bf16x8_t*)(Bb + (wc * 64 + j * 16 + lrow) * 64 + lko);
#pragma unroll
        for (int i = 0; i < 4; ++i)
#pragma unroll
            for (int j = 0; j < 4; ++j)
                acc[i][j] = __builtin_amdgcn_mfma_f32_16x16x32_bf16(af[i], bfg[j], acc[i][j], 0, 0, 0);
        __syncthreads();
        cur ^= 1;
    }

    const int rbase = m0 + wr * 64 + ((l >> 4) << 2);
    const int cbase = n0 + wc * 64 + (l & 15);
    if (MODE == 0) {
#pragma unroll
        for (int j = 0; j < 4; ++j) {
            int col = cbase + j * 16;
            int mat = col >> 11;
            int nn = col & 2047;
            int h = nn >> 7, hd = nn & 127;
            unsigned short* outp = (mat == 0) ? outQ : ((mat == 1) ? outK : outV);
#pragma unroll
            for (int i = 0; i < 4; ++i) {
#pragma unroll
                for (int r = 0; r < 4; ++r) {
                    int row = rbase + i * 16 + r;
                    int b = row >> 11, s = row & 2047;
                    outp[((size_t)(b * HH + h) * SS + s) * HDD + hd] = f2bf(acc[i][j][r]);
                }
            }
        }
    } else {
#pragma unroll
        for (int j = 0; j < 4; ++j) {
            int col = cbase + j * 16;
            float bv = bias[col];
#pragma unroll
            for (int i = 0; i < 4; ++i) {
#pragma unroll
                for (int r = 0; r < 4; ++r) {
                    int row = rbase + i * 16 + r;
                    outF[(size_t)row * DD + col] = acc[i][j][r] + bv;
                }
            }
        }
    }
}

// ---------------- flash attention: per (qt, h, b), 64 q-rows/block, 4 waves ----------------
__global__ __launch_bounds__(256, 2) void attn_kernel(
    const unsigned short* __restrict__ Q, const unsigned short* __restrict__ K,
    const unsigned short* __restrict__ VT, unsigned short* __restrict__ ctx) {
    __shared__ __attribute__((aligned(16))) unsigned short Ks[64 * 128];
    __shared__ __attribute__((aligned(16))) unsigned short Vs[128 * 64];
    __shared__ __attribute__((aligned(16))) unsigned short Ps[64 * 72];
    const int tid = threadIdx.x, w = tid >> 6, l = tid & 63;
    const int qt = blockIdx.x, h = blockIdx.y, b = blockIdx.z;
    const int bh = b * HH + h;
    const int q0 = qt * 64;
    const float scale = 0.08838834764831845f;

    const unsigned short* Qbh = Q + (size_t)bh * SS * HDD;
    const unsigned short* Kbh = K + (size_t)bh * SS * HDD;
    const unsigned short* Vbh = VT + (size_t)bh * HDD * SS;

    const int qrow = q0 + w * 16 + (l & 15);
    bf16x8_t qf[4];
#pragma unroll
    for (int ks = 0; ks < 4; ++ks)
        qf[ks] = *(const bf16x8_t*)(Qbh + (size_t)qrow * HDD + ks * 32 + (l >> 4) * 8);

    float m_r[4], l_r[4];
#pragma unroll
    for (int r = 0; r < 4; ++r) { m_r[r] = -1e30f; l_r[r] = 0.f; }
    f32x4 o[8] = {};

    for (int kt = 0; kt <= qt; ++kt) {
        const int kv0 = kt * 64;
        // stage K tile [64][128] (swizzled: lds linear, global source pre-swizzled)
#pragma unroll
        for (int iss = 0; iss < 4; ++iss) {
            int p0 = w * 4096 + iss * 1024;
            int p = p0 + l * 16;
            int row = p >> 8;
            int cb = p & 255;
            const char* g = (const char*)Kbh + (size_t)(kv0 + row) * 256 + (cb ^ ((row & 7) << 4));
            gload_lds16(g, (char*)Ks + p0);
        }
        // stage VT tile [128][64]
#pragma unroll
        for (int iss = 0; iss < 4; ++iss) {
            int p0 = w * 4096 + iss * 1024;
            int p = p0 + l * 16;
            int row = p >> 7;
            int cb = p & 127;
            const char* g = (const char*)Vbh + (size_t)row * (SS * 2) + (size_t)kv0 * 2 + (cb ^ ((row & 7) << 4));
            gload_lds16(g, (char*)Vs + p0);
        }
        __syncthreads();

        // S = Q @ K^T  (16x64 per wave)
        f32x4 sf[4] = {};
#pragma unroll
        for (int c = 0; c < 4; ++c) {
            int krow = c * 16 + (l & 15);
#pragma unroll
            for (int ks = 0; ks < 4; ++ks) {
                int lb = ks * 64 + (l >> 4) * 16;
                bf16x8_t kb = *(const bf16x8_t*)((const char*)Ks + krow * 256 + (lb ^ ((krow & 7) << 4)));
                sf[c] = __builtin_amdgcn_mfma_f32_16x16x32_bf16(qf[ks], kb, sf[c], 0, 0, 0);
            }
        }

        // scale + causal mask
        const bool diag = (kt == qt);
#pragma unroll
        for (int c = 0; c < 4; ++c) {
#pragma unroll
            for (int r = 0; r < 4; ++r) {
                float v = sf[c][r] * scale;
                if (diag) {
                    int col = kv0 + c * 16 + (l & 15);
                    int row = q0 + w * 16 + ((l >> 4) << 2) + r;
                    if (col > row) v = -1e30f;
                }
                sf[c][r] = v;
            }
        }
        // online softmax
        float alpha[4];
#pragma unroll
        for (int r = 0; r < 4; ++r) {
            float mx = fmaxf(fmaxf(sf[0][r], sf[1][r]), fmaxf(sf[2][r], sf[3][r]));
#pragma unroll
            for (int off = 1; off < 16; off <<= 1) mx = fmaxf(mx, __shfl_xor(mx, off));
            float mnew = fmaxf(m_r[r], mx);
            alpha[r] = __expf(m_r[r] - mnew);
            m_r[r] = mnew;
        }
        float psum[4] = {0.f, 0.f, 0.f, 0.f};
#pragma unroll
        for (int c = 0; c < 4; ++c) {
#pragma unroll
            for (int r = 0; r < 4; ++r) {
                float p = __expf(sf[c][r] - m_r[r]);
                psum[r] += p;
                sf[c][r] = p;
            }
        }
#pragma unroll
        for (int r = 0; r < 4; ++r) {
            float s = psum[r];
#pragma unroll
            for (int off = 1; off < 16; off <<= 1) s += __shfl_xor(s, off);
            l_r[r] = l_r[r] * alpha[r] + s;
        }
#pragma unroll
        for (int j = 0; j < 8; ++j)
#pragma unroll
            for (int r = 0; r < 4; ++r) o[j][r] *= alpha[r];
        // P -> LDS (wave-private rows, padded stride 72 shorts = 144B)
#pragma unroll
        for (int c = 0; c < 4; ++c)
#pragma unroll
            for (int r = 0; r < 4; ++r) {
                int row = w * 16 + ((l >> 4) << 2) + r;
                Ps[row * 72 + c * 16 + (l & 15)] = f2bf(sf[c][r]);
            }
        // O += P @ V
#pragma unroll
        for (int ks2 = 0; ks2 < 2; ++ks2) {
            bf16x8_t pa = *(const bf16x8_t*)((const char*)Ps + (w * 16 + (l & 15)) * 144 + ks2 * 64 + (l >> 4) * 16);
#pragma unroll
            for (int j = 0; j < 8; ++j) {
                int vrow = j * 16 + (l & 15);
                int lb = ks2 * 64 + (l >> 4) * 16;
                bf16x8_t vb = *(const bf16x8_t*)((const char*)Vs + vrow * 128 + (lb ^ ((vrow & 7) << 4)));
                o[j] = __builtin_amdgcn_mfma_f32_16x16x32_bf16(pa, vb, o[j], 0, 0, 0);
            }
        }
        __syncthreads();
    }

    // epilogue: ctx[b][s][h][hd] bf16
    unsigned short* cb_ = ctx + (size_t)b * SS * DD + (size_t)h * HDD;
#pragma unroll
    for (int r = 0; r < 4; ++r) {
        int row = q0 + w * 16 + ((l >> 4) << 2) + r;
        float inv = 1.f / l_r[r];
#pragma unroll
        for (int j = 0; j < 8; ++j)
            cb_[(size_t)row * DD + j * 16 + (l & 15)] = f2bf(o[j][r] * inv);
    }
}

extern "C" void kernel_launch(void* const* d_in, const int* in_sizes, int n_in,
                              void* d_out, int out_size, void* d_ws, size_t ws_size,
                              hipStream_t stream) {
    (void)in_sizes; (void)n_in; (void)out_size; (void)ws_size;
    const float* x  = (const float*)d_in[0];
    const float* Wq = (const float*)d_in[1];
    const float* Wk = (const float*)d_in[2];
    const float* Wv = (const float*)d_in[3];
    const float* Wo = (const float*)d_in[4];
    const float* bo = (const float*)d_in[5];

    char* ws = (char*)d_ws;
    // layout (bytes): xb 0..32M (reused as ctx), WqkvT 32..56M, WoT 56..64M,
    // Q 64..96M, K 96..128M, V 128..160M, VT 160..192M
    unsigned short* xb    = (unsigned short*)(ws);
    unsigned short* WqkvT = (unsigned short*)(ws + (32u << 20));
    unsigned short* WoT   = (unsigned short*)(ws + (56u << 20));
    unsigned short* Qb    = (unsigned short*)(ws + (64u << 20));
    unsigned short* Kb    = (unsigned short*)(ws + (96u << 20));
    unsigned short* Vb    = (unsigned short*)(ws + (128u << 20));
    unsigned short* VTb   = (unsigned short*)(ws + (160u << 20));
    unsigned short* ctx   = xb;  // xb dead after QKV GEMM

    convert_x<<<4096, 256, 0, stream>>>(x, xb, BB * SS * DD);
    transpose_w<<<dim3(64, 64, 4), dim3(32, 8), 0, stream>>>(Wq, Wk, Wv, Wo, WqkvT, WoT);
    // QKV fused GEMM: [8192][2048] x [2048][6144]
    gemm_bt<0><<<dim3(48, 64), 256, 0, stream>>>(xb, WqkvT, Qb, Kb, Vb, nullptr, nullptr);
    transpose_v<<<dim3(SS / 32, HDD / 32, BB * HH), dim3(32, 8), 0, stream>>>(Vb, VTb);
    attn_kernel<<<dim3(SS / 64, HH, BB), 256, 0, stream>>>(Qb, Kb, VTb, ctx);
    // out = ctx @ Wo + bo
    gemm_bt<1><<<dim3(16, 64), 256, 0, stream>>>(ctx, WoT, nullptr, nullptr, nullptr, (float*)d_out, bo);
}